// Round 1
// baseline (1942.782 us; speedup 1.0000x reference)
//
#include <hip/hip_runtime.h>

typedef __attribute__((ext_vector_type(4))) float f32x4;
typedef __attribute__((ext_vector_type(8))) short bf16x8;

#define NHEADS 96
#define SEQ 1024
#define DIM 256
#define QBLK 128
#define KVB 32
#define NWAVES 8

__device__ __forceinline__ unsigned short f2bf(float x) {
  unsigned int u = __float_as_uint(x);
  unsigned int r = (u + 0x7fffu + ((u >> 16) & 1u)) >> 16;  // RNE
  return (unsigned short)r;
}
__device__ __forceinline__ float bf2f(unsigned short h) {
  return __uint_as_float(((unsigned int)h) << 16);
}

// ---- cos/sin tables: replicate reference phases exactly in fp32 ----
__global__ void k_tables(const float* __restrict__ freqs,
                         float* __restrict__ cosT, float* __restrict__ sinT) {
  int i = blockIdx.x * 256 + threadIdx.x;   // 1024*128
  int t = i >> 7, d = i & 127;
  float ph = fmodf((float)t * freqs[d], 1.0f) * 6.28318530717958647692f;
  float s, c;
  sincosf(ph, &s, &c);
  cosT[i] = c;
  sinT[i] = s;
}

// ---- rope(Q) -> bf16 hi/lo split, row-major [head][t][n] ----
__global__ void k_rope(const float* __restrict__ Q, const float* __restrict__ cosT,
                       const float* __restrict__ sinT,
                       unsigned short* __restrict__ QRhi, unsigned short* __restrict__ QRlo) {
  size_t idx = (size_t)blockIdx.x * 256 + threadIdx.x;  // one float4 each; 6291456 total
  int n4 = (int)(idx & 63);
  size_t row = idx >> 6;            // head*1024 + t
  int t = (int)(row & 1023);
  float4 q = reinterpret_cast<const float4*>(Q)[idx];
  int i0 = n4 << 2;
  int d0 = i0 & 127;                // freq index = element index mod 128 (reference quirk)
  float4 c4 = *reinterpret_cast<const float4*>(cosT + t * 128 + d0);
  float4 s4 = *reinterpret_cast<const float4*>(sinT + t * 128 + d0);
  // pairs (i0,i0+1),(i0+2,i0+3): even -> q*cos - q_odd*sin ; odd -> q*cos + q_even*sin
  float r0 = q.x * c4.x - q.y * s4.x;
  float r1 = q.y * c4.y + q.x * s4.y;
  float r2 = q.z * c4.z - q.w * s4.z;
  float r3 = q.w * c4.w + q.z * s4.w;
  unsigned short h0 = f2bf(r0), h1 = f2bf(r1), h2 = f2bf(r2), h3 = f2bf(r3);
  ushort4 H; H.x = h0; H.y = h1; H.z = h2; H.w = h3;
  ushort4 L;
  L.x = f2bf(r0 - bf2f(h0));
  L.y = f2bf(r1 - bf2f(h1));
  L.z = f2bf(r2 - bf2f(h2));
  L.w = f2bf(r3 - bf2f(h3));
  reinterpret_cast<ushort4*>(QRhi)[idx] = H;
  reinterpret_cast<ushort4*>(QRlo)[idx] = L;
}

// ---- V -> bf16 hi/lo, transposed per head: Vt[head][n=256][s=1024] ----
__global__ void k_vsplit(const float* __restrict__ V,
                         unsigned short* __restrict__ Vthi, unsigned short* __restrict__ Vtlo) {
  __shared__ float tile[32][33];
  int h = blockIdx.z;
  int n0 = blockIdx.x * 32;
  int s0 = blockIdx.y * 32;
  int tx = threadIdx.x & 31, ty = threadIdx.x >> 5;  // 32 x 8
  const float* src = V + ((size_t)h * SEQ + s0) * DIM + n0;
#pragma unroll
  for (int r = 0; r < 32; r += 8) tile[ty + r][tx] = src[(size_t)(ty + r) * DIM + tx];
  __syncthreads();
  size_t dbase = ((size_t)h * DIM + n0) * SEQ + s0;
#pragma unroll
  for (int r = 0; r < 32; r += 8) {
    float v = tile[tx][ty + r];
    unsigned short hi = f2bf(v);
    unsigned short lo = f2bf(v - bf2f(hi));
    Vthi[dbase + (size_t)(ty + r) * SEQ + tx] = hi;
    Vtlo[dbase + (size_t)(ty + r) * SEQ + tx] = lo;
  }
}

// ---- flash attention, split-bf16 3-term compensated MFMA ----
__global__ __launch_bounds__(512, 2)
void k_attn(const unsigned short* __restrict__ QRhi, const unsigned short* __restrict__ QRlo,
            const unsigned short* __restrict__ Vthi, const unsigned short* __restrict__ Vtlo,
            float* __restrict__ Out) {
  // XCD swizzle: head h -> XCD h%8, so a head's 8 q-blocks share one L2
  int x = blockIdx.x;        // 768 = 96 heads * 8 qblocks
  int xcd = x & 7;
  int r = x >> 3;            // 0..95
  int hh = r % 12;
  int qb = r / 12;           // 0..7
  int head = hh * 8 + xcd;

  int tid = threadIdx.x;
  int w = tid >> 6;
  int lane = tid & 63;
  int lg = lane >> 4;        // lane group 0..3
  int lc = lane & 15;
  int q0 = qb * QBLK + w * 16;

  __shared__ alignas(16) unsigned short pls[NWAVES][2][16 * 40];
  unsigned short* pH = &pls[w][0][0];
  unsigned short* pL = &pls[w][1][0];

  // Q fragments resident: A-frag row = lc, k = c*32 + lg*8 + e
  bf16x8 qh[8], ql[8];
  {
    const size_t qbase = ((size_t)(head * SEQ + q0 + lc)) * DIM + lg * 8;
#pragma unroll
    for (int c = 0; c < 8; c++) {
      qh[c] = *reinterpret_cast<const bf16x8*>(QRhi + qbase + c * 32);
      ql[c] = *reinterpret_cast<const bf16x8*>(QRlo + qbase + c * 32);
    }
  }

  f32x4 acc[16];
#pragma unroll
  for (int i = 0; i < 16; i++) acc[i] = (f32x4){0.f, 0.f, 0.f, 0.f};
  float mrow[4] = {-__builtin_inff(), -__builtin_inff(), -__builtin_inff(), -__builtin_inff()};
  float lrow[4] = {0.f, 0.f, 0.f, 0.f};
  const float scale = 0.0625f;  // 1/sqrt(256)

  for (int s0 = 0; s0 < SEQ; s0 += KVB) {
    // ---- S = QR_q . QR_k^T  (3-term hi/lo compensation) ----
    f32x4 sA = (f32x4){0.f, 0.f, 0.f, 0.f};
    f32x4 sB = (f32x4){0.f, 0.f, 0.f, 0.f};
    const size_t kb = ((size_t)(head * SEQ + s0 + lc)) * DIM + lg * 8;
#pragma unroll
    for (int c = 0; c < 8; c++) {
      bf16x8 k0h = *reinterpret_cast<const bf16x8*>(QRhi + kb + c * 32);
      bf16x8 k0l = *reinterpret_cast<const bf16x8*>(QRlo + kb + c * 32);
      bf16x8 k1h = *reinterpret_cast<const bf16x8*>(QRhi + kb + 16 * DIM + c * 32);
      bf16x8 k1l = *reinterpret_cast<const bf16x8*>(QRlo + kb + 16 * DIM + c * 32);
      sA = __builtin_amdgcn_mfma_f32_16x16x32_bf16(qh[c], k0h, sA, 0, 0, 0);
      sA = __builtin_amdgcn_mfma_f32_16x16x32_bf16(qh[c], k0l, sA, 0, 0, 0);
      sA = __builtin_amdgcn_mfma_f32_16x16x32_bf16(ql[c], k0h, sA, 0, 0, 0);
      sB = __builtin_amdgcn_mfma_f32_16x16x32_bf16(qh[c], k1h, sB, 0, 0, 0);
      sB = __builtin_amdgcn_mfma_f32_16x16x32_bf16(qh[c], k1l, sB, 0, 0, 0);
      sB = __builtin_amdgcn_mfma_f32_16x16x32_bf16(ql[c], k1h, sB, 0, 0, 0);
    }
    // ---- online softmax: lane holds rows lg*4+j (j=0..3), col lc / 16+lc ----
    float p0[4], p1[4], fr[4];
#pragma unroll
    for (int j = 0; j < 4; j++) {
      float a = sA[j] * scale, b = sB[j] * scale;
      float mx = fmaxf(a, b);
      mx = fmaxf(mx, __shfl_xor(mx, 1, 64));
      mx = fmaxf(mx, __shfl_xor(mx, 2, 64));
      mx = fmaxf(mx, __shfl_xor(mx, 4, 64));
      mx = fmaxf(mx, __shfl_xor(mx, 8, 64));
      float mnew = fmaxf(mrow[j], mx);
      float f = __expf(mrow[j] - mnew);   // first iter: exp(-inf)=0
      mrow[j] = mnew;
      float e0 = __expf(a - mnew), e1 = __expf(b - mnew);
      float rs = e0 + e1;
      rs += __shfl_xor(rs, 1, 64);
      rs += __shfl_xor(rs, 2, 64);
      rs += __shfl_xor(rs, 4, 64);
      rs += __shfl_xor(rs, 8, 64);
      lrow[j] = lrow[j] * f + rs;
      p0[j] = e0; p1[j] = e1; fr[j] = f;
    }
#pragma unroll
    for (int nt = 0; nt < 16; nt++)
#pragma unroll
      for (int j = 0; j < 4; j++) acc[nt][j] *= fr[j];

    // ---- P -> bf16 hi/lo, transpose C-layout -> A-layout via wave-private LDS ----
#pragma unroll
    for (int j = 0; j < 4; j++) {
      int R = lg * 4 + j;
      unsigned short h0 = f2bf(p0[j]);
      unsigned short h1 = f2bf(p1[j]);
      pH[R * 40 + lc] = h0;
      pH[R * 40 + 16 + lc] = h1;
      pL[R * 40 + lc] = f2bf(p0[j] - bf2f(h0));
      pL[R * 40 + 16 + lc] = f2bf(p1[j] - bf2f(h1));
    }
    asm volatile("s_waitcnt lgkmcnt(0)" ::: "memory");
    bf16x8 paH = *reinterpret_cast<const bf16x8*>(pH + lc * 40 + lg * 8);
    bf16x8 paL = *reinterpret_cast<const bf16x8*>(pL + lc * 40 + lg * 8);
    asm volatile("" ::: "memory");

    // ---- acc += P . V  (3-term) ; V B-frag from transposed Vt rows ----
    const size_t vb = ((size_t)(head * DIM + lc)) * SEQ + s0 + lg * 8;
#pragma unroll
    for (int nt = 0; nt < 16; nt++) {
      bf16x8 vh = *reinterpret_cast<const bf16x8*>(Vthi + vb + (size_t)nt * 16 * SEQ);
      bf16x8 vl = *reinterpret_cast<const bf16x8*>(Vtlo + vb + (size_t)nt * 16 * SEQ);
      acc[nt] = __builtin_amdgcn_mfma_f32_16x16x32_bf16(paH, vh, acc[nt], 0, 0, 0);
      acc[nt] = __builtin_amdgcn_mfma_f32_16x16x32_bf16(paL, vh, acc[nt], 0, 0, 0);
      acc[nt] = __builtin_amdgcn_mfma_f32_16x16x32_bf16(paH, vl, acc[nt], 0, 0, 0);
    }
  }

  // ---- epilogue: out = acc / rowsum ----
#pragma unroll
  for (int j = 0; j < 4; j++) {
    float inv = 1.0f / lrow[j];
    size_t obase = ((size_t)(head * SEQ + q0 + lg * 4 + j)) * DIM + lc;
#pragma unroll
    for (int nt = 0; nt < 16; nt++) Out[obase + nt * 16] = acc[nt][j] * inv;
  }
}

extern "C" void kernel_launch(void* const* d_in, const int* in_sizes, int n_in,
                              void* d_out, int out_size, void* d_ws, size_t ws_size,
                              hipStream_t stream) {
  const float* Q = (const float*)d_in[0];
  const float* V = (const float*)d_in[1];
  const float* freqs = (const float*)d_in[2];
  float* Out = (float*)d_out;

  char* ws = (char*)d_ws;
  float* cosT = (float*)ws;                               // 1024*128*4 = 512 KiB
  float* sinT = (float*)(ws + 524288);                    // 512 KiB
  unsigned short* QRhi = (unsigned short*)(ws + 1048576); // 96*1024*256*2 = 48 MiB
  unsigned short* QRlo = QRhi + 25165824;
  unsigned short* Vthi = QRlo + 25165824;
  unsigned short* Vtlo = Vthi + 25165824;

  k_tables<<<512, 256, 0, stream>>>(freqs, cosT, sinT);
  k_rope<<<24576, 256, 0, stream>>>(Q, cosT, sinT, QRhi, QRlo);
  k_vsplit<<<dim3(8, 32, 96), 256, 0, stream>>>(V, Vthi, Vtlo);
  k_attn<<<768, 512, 0, stream>>>(QRhi, QRlo, Vthi, Vtlo, Out);
}

// Round 2
// 631.378 us; speedup vs baseline: 3.0770x; 3.0770x over previous
//
#include <hip/hip_runtime.h>

typedef __attribute__((ext_vector_type(4))) float f32x4;
typedef __attribute__((ext_vector_type(8))) short bf16x8;

#define SEQ 1024
#define DIM 256
#define NT32 32           // 32-row KV tiles per head
#define TILE_SHORTS 8192  // 16 KB tile image (32 x 256 bf16)

__device__ __forceinline__ unsigned short f2bf(float x) {
  unsigned int u = __float_as_uint(x);
  unsigned int r = (u + 0x7fffu + ((u >> 16) & 1u)) >> 16;  // RNE
  return (unsigned short)r;
}
__device__ __forceinline__ float bf2f(unsigned short h) {
  return __uint_as_float(((unsigned int)h) << 16);
}

// ---- cos/sin tables: replicate reference phases exactly in fp32 ----
__global__ void k_tables(const float* __restrict__ freqs,
                         float* __restrict__ cosT, float* __restrict__ sinT) {
  int i = blockIdx.x * 256 + threadIdx.x;   // 1024*128
  int t = i >> 7, d = i & 127;
  float ph = fmodf((float)t * freqs[d], 1.0f) * 6.28318530717958647692f;
  float s, c;
  sincosf(ph, &s, &c);
  cosT[i] = c;
  sinT[i] = s;
}

// ---- rope(Q) -> bf16 hi/lo, TILED layout: [head][st][c][lg][sl][8] ----
__global__ void k_rope_tiled(const float* __restrict__ Q, const float* __restrict__ cosT,
                             const float* __restrict__ sinT,
                             unsigned short* __restrict__ KThi, unsigned short* __restrict__ KTlo) {
  int idx = blockIdx.x * 256 + threadIdx.x;   // 96*32*8*4*32 = 3,145,728 chunks
  int sl = idx & 31;
  int lg = (idx >> 5) & 3;
  int c  = (idx >> 7) & 7;
  int st = (idx >> 10) & 31;
  int head = idx >> 15;
  int s = st * 32 + sl;
  int n0 = c * 32 + lg * 8;
  const float* qp = Q + ((size_t)(head * SEQ + s)) * DIM + n0;
  float4 a = *(const float4*)qp;
  float4 b = *(const float4*)(qp + 4);
  int d0 = n0 & 127;
  const float* cp = cosT + s * 128 + d0;
  const float* sp = sinT + s * 128 + d0;
  float4 ca = *(const float4*)cp, cb = *(const float4*)(cp + 4);
  float4 sa = *(const float4*)sp, sb = *(const float4*)(sp + 4);
  float r0 = a.x * ca.x - a.y * sa.x;
  float r1 = a.y * ca.y + a.x * sa.y;
  float r2 = a.z * ca.z - a.w * sa.z;
  float r3 = a.w * ca.w + a.z * sa.w;
  float r4 = b.x * cb.x - b.y * sb.x;
  float r5 = b.y * cb.y + b.x * sb.y;
  float r6 = b.z * cb.z - b.w * sb.z;
  float r7 = b.w * cb.w + b.z * sb.w;
  bf16x8 H, L;
  unsigned short h;
  h = f2bf(r0); H[0] = (short)h; L[0] = (short)f2bf(r0 - bf2f(h));
  h = f2bf(r1); H[1] = (short)h; L[1] = (short)f2bf(r1 - bf2f(h));
  h = f2bf(r2); H[2] = (short)h; L[2] = (short)f2bf(r2 - bf2f(h));
  h = f2bf(r3); H[3] = (short)h; L[3] = (short)f2bf(r3 - bf2f(h));
  h = f2bf(r4); H[4] = (short)h; L[4] = (short)f2bf(r4 - bf2f(h));
  h = f2bf(r5); H[5] = (short)h; L[5] = (short)f2bf(r5 - bf2f(h));
  h = f2bf(r6); H[6] = (short)h; L[6] = (short)f2bf(r6 - bf2f(h));
  h = f2bf(r7); H[7] = (short)h; L[7] = (short)f2bf(r7 - bf2f(h));
  *(bf16x8*)(KThi + (size_t)idx * 8) = H;
  *(bf16x8*)(KTlo + (size_t)idx * 8) = L;
}

// ---- V -> bf16 hi/lo, TILED transposed layout: [head][st][sb][n][8] ----
__global__ void k_vsplit_tiled(const float* __restrict__ V,
                               unsigned short* __restrict__ VThi, unsigned short* __restrict__ VTlo) {
  __shared__ float vt[32][260];
  int bid = blockIdx.x;        // 96*32 = 3072
  int head = bid >> 5;
  int st = bid & 31;
  int t = threadIdx.x;
  const float* src = V + ((size_t)(head * SEQ + st * 32)) * DIM;
#pragma unroll
  for (int k = 0; k < 8; k++) {
    int f4 = t + k * 256;            // 0..2047 float4 chunks, fully coalesced
    int row = f4 >> 6;
    int c4 = f4 & 63;
    float4 v = *(const float4*)(src + (size_t)row * DIM + c4 * 4);
    *(float4*)&vt[row][c4 * 4] = v;  // 260*4=1040B rows keep 16B alignment
  }
  __syncthreads();
  int n = t;
  size_t dbase = ((size_t)(head * 32 + st)) * TILE_SHORTS;
#pragma unroll
  for (int sb = 0; sb < 4; sb++) {
    bf16x8 H, L;
#pragma unroll
    for (int e = 0; e < 8; e++) {
      float f = vt[sb * 8 + e][n];
      unsigned short hh = f2bf(f);
      H[e] = (short)hh;
      L[e] = (short)f2bf(f - bf2f(hh));
    }
    *(bf16x8*)(VThi + dbase + (size_t)(sb * 256 + n) * 8) = H;
    *(bf16x8*)(VTlo + dbase + (size_t)(sb * 256 + n) * 8) = L;
  }
}

// wave w stages half (w&1) of region (w>>1); 8 x 1KB global_load_lds per wave
__device__ __forceinline__ void stage_tile(const unsigned short* rb, size_t toff,
                                           unsigned short* ldsbase, int w, int lane) {
  int half = w & 1;
#pragma unroll
  for (int j = 0; j < 8; j++) {
    const unsigned short* src = rb + toff + half * 4096 + j * 512 + lane * 8;
    unsigned short* dst = ldsbase + (w * 4096 + j * 512);
    __builtin_amdgcn_global_load_lds(
        (const __attribute__((address_space(1))) unsigned int*)src,
        (__attribute__((address_space(3))) unsigned int*)dst, 16, 0, 0);
  }
}

// ---- flash attention: LDS-staged, double-buffered, counted vmcnt ----
__global__ __launch_bounds__(512, 2)
void k_attn(const unsigned short* __restrict__ KThi, const unsigned short* __restrict__ KTlo,
            const unsigned short* __restrict__ VThi, const unsigned short* __restrict__ VTlo,
            float* __restrict__ Out) {
  int x = blockIdx.x;        // 768 = 96 heads * 8 qblocks
  int xcd = x & 7;
  int r = x >> 3;            // 0..95
  int hh = r % 12;
  int qb = r / 12;           // 0..7
  int head = hh * 8 + xcd;   // all 8 q-blocks of a head land on one XCD

  int tid = threadIdx.x;
  int w = tid >> 6;
  int lane = tid & 63;
  int lg = lane >> 4;
  int lc = lane & 15;
  int q0 = qb * 128 + w * 16;

  __shared__ alignas(16) unsigned short kv[2][32768];     // [Khi|Klo|Vhi|Vlo] x 16KB
  __shared__ alignas(16) unsigned short pls[8][2][640];   // per-wave P transpose (16x40)
  unsigned short* pH = &pls[w][0][0];
  unsigned short* pL = &pls[w][1][0];

  // Q fragments from the tiled layout (resident in VGPRs)
  bf16x8 qh[8], ql[8];
  {
    int st_q = qb * 4 + (w >> 1);
    int slb = (w & 1) * 16;
    size_t qtile = ((size_t)(head * 32 + st_q)) * TILE_SHORTS;
#pragma unroll
    for (int c = 0; c < 8; c++) {
      size_t o = qtile + (size_t)((c * 4 + lg) * 256 + (slb + lc) * 8);
      qh[c] = *(const bf16x8*)(KThi + o);
      ql[c] = *(const bf16x8*)(KTlo + o);
    }
  }

  f32x4 acc[16];
#pragma unroll
  for (int i = 0; i < 16; i++) acc[i] = (f32x4){0.f, 0.f, 0.f, 0.f};
  float mrow[4] = {-__builtin_inff(), -__builtin_inff(), -__builtin_inff(), -__builtin_inff()};
  float lrow[4] = {0.f, 0.f, 0.f, 0.f};
  const float scale = 0.0625f;  // 1/sqrt(256)

  int r4 = w >> 1;
  const unsigned short* rb = (r4 == 0) ? KThi : (r4 == 1) ? KTlo : (r4 == 2) ? VThi : VTlo;
  size_t hbase = (size_t)head * NT32 * TILE_SHORTS;

  stage_tile(rb, hbase, &kv[0][0], w, lane);   // prologue: tile 0

  for (int t = 0; t < 32; ++t) {
    int cur = t & 1;
    if (t < 31) {
      stage_tile(rb, hbase + (size_t)(t + 1) * TILE_SHORTS, &kv[cur ^ 1][0], w, lane);
      asm volatile("s_waitcnt vmcnt(8)" ::: "memory");   // cur tile done, next 8 in flight
    } else {
      asm volatile("s_waitcnt vmcnt(0)" ::: "memory");
    }
    __builtin_amdgcn_s_barrier();

    const unsigned short* bK = &kv[cur][0];
    const unsigned short* bV = &kv[cur][16384];

    // ---- S = Q . K^T (3-term hi/lo compensation), K frags from LDS ----
    f32x4 sA = (f32x4){0.f, 0.f, 0.f, 0.f};
    f32x4 sB = (f32x4){0.f, 0.f, 0.f, 0.f};
#pragma unroll
    for (int c = 0; c < 8; c++) {
      int ofs = (c * 4 + lg) * 256 + lc * 8;
      bf16x8 k0h = *(const bf16x8*)(bK + ofs);
      bf16x8 k0l = *(const bf16x8*)(bK + 8192 + ofs);
      bf16x8 k1h = *(const bf16x8*)(bK + ofs + 128);
      bf16x8 k1l = *(const bf16x8*)(bK + 8192 + ofs + 128);
      sA = __builtin_amdgcn_mfma_f32_16x16x32_bf16(qh[c], k0h, sA, 0, 0, 0);
      sA = __builtin_amdgcn_mfma_f32_16x16x32_bf16(qh[c], k0l, sA, 0, 0, 0);
      sA = __builtin_amdgcn_mfma_f32_16x16x32_bf16(ql[c], k0h, sA, 0, 0, 0);
      sB = __builtin_amdgcn_mfma_f32_16x16x32_bf16(qh[c], k1h, sB, 0, 0, 0);
      sB = __builtin_amdgcn_mfma_f32_16x16x32_bf16(qh[c], k1l, sB, 0, 0, 0);
      sB = __builtin_amdgcn_mfma_f32_16x16x32_bf16(ql[c], k1h, sB, 0, 0, 0);
    }

    // ---- online softmax (rows lg*4+j, cols lc / 16+lc) ----
    float p0[4], p1[4], fr[4];
#pragma unroll
    for (int j = 0; j < 4; j++) {
      float a = sA[j] * scale, b = sB[j] * scale;
      float mx = fmaxf(a, b);
      mx = fmaxf(mx, __shfl_xor(mx, 1, 64));
      mx = fmaxf(mx, __shfl_xor(mx, 2, 64));
      mx = fmaxf(mx, __shfl_xor(mx, 4, 64));
      mx = fmaxf(mx, __shfl_xor(mx, 8, 64));
      float mnew = fmaxf(mrow[j], mx);
      float f = __expf(mrow[j] - mnew);
      mrow[j] = mnew;
      float e0 = __expf(a - mnew), e1 = __expf(b - mnew);
      float rs = e0 + e1;
      rs += __shfl_xor(rs, 1, 64);
      rs += __shfl_xor(rs, 2, 64);
      rs += __shfl_xor(rs, 4, 64);
      rs += __shfl_xor(rs, 8, 64);
      lrow[j] = lrow[j] * f + rs;
      p0[j] = e0; p1[j] = e1; fr[j] = f;
    }
#pragma unroll
    for (int nt = 0; nt < 16; nt++)
#pragma unroll
      for (int j = 0; j < 4; j++) acc[nt][j] *= fr[j];

    // ---- P -> bf16 hi/lo, C-layout -> A-layout via wave-private LDS ----
#pragma unroll
    for (int j = 0; j < 4; j++) {
      int R = lg * 4 + j;
      unsigned short h0 = f2bf(p0[j]);
      unsigned short h1 = f2bf(p1[j]);
      pH[R * 40 + lc] = h0;
      pH[R * 40 + 16 + lc] = h1;
      pL[R * 40 + lc] = f2bf(p0[j] - bf2f(h0));
      pL[R * 40 + 16 + lc] = f2bf(p1[j] - bf2f(h1));
    }
    asm volatile("s_waitcnt lgkmcnt(0)" ::: "memory");
    bf16x8 paH = *(const bf16x8*)(pH + lc * 40 + lg * 8);
    bf16x8 paL = *(const bf16x8*)(pL + lc * 40 + lg * 8);
    asm volatile("" ::: "memory");

    // ---- acc += P . V (3-term), V frags from LDS ----
#pragma unroll
    for (int nt = 0; nt < 16; nt++) {
      int vo = lg * 2048 + nt * 128 + lc * 8;
      bf16x8 vh = *(const bf16x8*)(bV + vo);
      bf16x8 vl = *(const bf16x8*)(bV + 8192 + vo);
      acc[nt] = __builtin_amdgcn_mfma_f32_16x16x32_bf16(paH, vh, acc[nt], 0, 0, 0);
      acc[nt] = __builtin_amdgcn_mfma_f32_16x16x32_bf16(paL, vh, acc[nt], 0, 0, 0);
      acc[nt] = __builtin_amdgcn_mfma_f32_16x16x32_bf16(paH, vl, acc[nt], 0, 0, 0);
    }
    __builtin_amdgcn_s_barrier();
  }

  // ---- epilogue ----
#pragma unroll
  for (int j = 0; j < 4; j++) {
    float inv = 1.0f / lrow[j];
    size_t obase = ((size_t)(head * SEQ + q0 + lg * 4 + j)) * DIM + lc;
#pragma unroll
    for (int nt = 0; nt < 16; nt++) Out[obase + nt * 16] = acc[nt][j] * inv;
  }
}

extern "C" void kernel_launch(void* const* d_in, const int* in_sizes, int n_in,
                              void* d_out, int out_size, void* d_ws, size_t ws_size,
                              hipStream_t stream) {
  const float* Q = (const float*)d_in[0];
  const float* V = (const float*)d_in[1];
  const float* freqs = (const float*)d_in[2];
  float* Out = (float*)d_out;

  char* ws = (char*)d_ws;
  float* cosT = (float*)ws;                               // 512 KiB
  float* sinT = (float*)(ws + 524288);                    // 512 KiB
  unsigned short* KThi = (unsigned short*)(ws + 1048576); // 48 MiB each
  unsigned short* KTlo = KThi + 25165824;
  unsigned short* VThi = KTlo + 25165824;
  unsigned short* VTlo = VThi + 25165824;

  k_tables<<<512, 256, 0, stream>>>(freqs, cosT, sinT);
  k_rope_tiled<<<12288, 256, 0, stream>>>(Q, cosT, sinT, KThi, KTlo);
  k_vsplit_tiled<<<3072, 256, 0, stream>>>(V, VThi, VTlo);
  k_attn<<<768, 512, 0, stream>>>(KThi, KTlo, VThi, VTlo, Out);
}